// Round 12
// baseline (319.242 us; speedup 1.0000x reference)
//
#include <hip/hip_runtime.h>
#include <hip/hip_bf16.h>

typedef __bf16 bf16x8 __attribute__((ext_vector_type(8)));
typedef float f32x4 __attribute__((ext_vector_type(4)));

#define NBLK_SC 256              // scatter blocks (chunks)
#define BKT_SH 8                 // 256 nodes per bucket
#define BKT_NODES 256

__device__ __forceinline__ unsigned short f2bf(float f) {
    unsigned int u = __float_as_uint(f);
    unsigned int r = (u + 0x7FFFu + ((u >> 16) & 1u)) >> 16;   // RNE
    return (unsigned short)r;
}
__device__ __forceinline__ float bflo(unsigned int u) { return __uint_as_float(u << 16); }
__device__ __forceinline__ float bfhi(unsigned int u) { return __uint_as_float(u & 0xffff0000u); }

// ---------------- fused prep: x->bf16 | W1/W2/W3 transpose+swizzle ----------------

__device__ __forceinline__ void prep_w_dev(const float* __restrict__ W,
                                           unsigned short* __restrict__ Wt,
                                           int DOUT, int i) {
    int col = i >> 4;
    int kblk = i & 15;
    size_t off = (size_t)col * 128 + (size_t)((kblk ^ (col & 7)) << 3);
#pragma unroll
    for (int j = 0; j < 8; j++)
        Wt[off + j] = f2bf(W[(kblk * 8 + j) * DOUT + col]);
}

__global__ __launch_bounds__(256) void prep_kernel(
    const float* __restrict__ x, unsigned short* __restrict__ Xb, int n4, int xblocks,
    const float* __restrict__ W1, unsigned short* __restrict__ Wt1,
    const float* __restrict__ W2, unsigned short* __restrict__ Wt2,
    const float* __restrict__ W3, unsigned short* __restrict__ Wt3) {
    int b = blockIdx.x;
    int tid = threadIdx.x;
    if (b < xblocks) {
        int i = b * 256 + tid;
        if (i < n4) {
            float4 v = reinterpret_cast<const float4*>(x)[i];
            ushort4 o;
            o.x = f2bf(v.x); o.y = f2bf(v.y); o.z = f2bf(v.z); o.w = f2bf(v.w);
            reinterpret_cast<ushort4*>(Xb)[i] = o;
        }
        return;
    }
    b -= xblocks;
    if (b < 8) {
        prep_w_dev(W1, Wt1, 128, b * 256 + tid);
    } else if (b < 16) {
        prep_w_dev(W2, Wt2, 128, (b - 8) * 256 + tid);
    } else {
        int i = (b - 16) * 256 + tid;
        if (i < 64 * 16) prep_w_dev(W3, Wt3, 64, i);
    }
}

// ---------------- CSR build: segmented counting sort (no global atomics) ----------------

// pass A: per-chunk histogram over buckets -> cnt[bucket*NBLK + chunk]
__global__ __launch_bounds__(256) void csr_hist_kernel(const int* __restrict__ dst,
                                                       int* __restrict__ cnt,
                                                       int E, int NBKT, int CPB) {
    __shared__ int lcnt[BKT_NODES];
    int j = blockIdx.x;
    int tid = threadIdx.x;
    lcnt[tid] = 0;
    __syncthreads();
    int e0 = j * CPB, e1 = min(e0 + CPB, E);
    for (int e = e0 + tid; e < e1; e += 256) atomicAdd(&lcnt[dst[e] >> BKT_SH], 1);
    __syncthreads();
    for (int b = tid; b < NBKT; b += 256) cnt[b * NBLK_SC + j] = lcnt[b];
}

// pass B: exclusive scan of cnt (total = NBKT*NBLK entries), one block
__global__ __launch_bounds__(1024) void csr_scan_kernel(const int* __restrict__ cnt,
                                                        int* __restrict__ scan, int total) {
    __shared__ int s[1024];
    int tid = threadIdx.x;
    int K = (total + 1023) / 1024;
    int i0 = tid * K;
    int i1 = min(i0 + K, total);
    int sum = 0;
    for (int i = i0; i < i1; i++) sum += cnt[i];
    s[tid] = sum;
    __syncthreads();
    for (int off = 1; off < 1024; off <<= 1) {
        int t = (tid >= off) ? s[tid - off] : 0;
        __syncthreads();
        s[tid] += t;
        __syncthreads();
    }
    int run = s[tid] - sum;
    for (int i = i0; i < i1; i++) { scan[i] = run; run += cnt[i]; }
}

// pass C: scatter into staged; each (bucket,chunk) segment has a single writer block
__global__ __launch_bounds__(256) void csr_scatter_kernel(const int* __restrict__ src,
                                                          const int* __restrict__ dst,
                                                          const float* __restrict__ ea,
                                                          const int* __restrict__ scan,
                                                          uint2* __restrict__ staged,
                                                          int E, int NBKT, int CPB) {
    __shared__ int curs[BKT_NODES];
    int j = blockIdx.x;
    int tid = threadIdx.x;
    for (int b = tid; b < NBKT; b += 256) curs[b] = scan[b * NBLK_SC + j];
    __syncthreads();
    int e0 = j * CPB, e1 = min(e0 + CPB, E);
    for (int e = e0 + tid; e < e1; e += 256) {
        int d = dst[e];
        int pos = atomicAdd(&curs[d >> BKT_SH], 1);
        staged[pos] = make_uint2((unsigned int)src[e] | ((unsigned int)f2bf(ea[e]) << 16),
                                 (unsigned int)(d & (BKT_NODES - 1)));
    }
}

// pass D: per bucket: LDS degree+scan -> row_off; in-bucket sort -> csr
__global__ __launch_bounds__(256) void csr_bucket_kernel(const int* __restrict__ scan,
                                                         const uint2* __restrict__ staged,
                                                         unsigned int* __restrict__ csr,
                                                         int* __restrict__ row_off,
                                                         int N, int E) {
    __shared__ int deg[BKT_NODES];
    __shared__ int loff[BKT_NODES];
    __shared__ int lcur[BKT_NODES];
    int b = blockIdx.x;
    int NBKT = gridDim.x;
    int tid = threadIdx.x;
    int base = scan[b * NBLK_SC];
    int end = (b == NBKT - 1) ? E : scan[(b + 1) * NBLK_SC];
    deg[tid] = 0;
    __syncthreads();
    for (int i = base + tid; i < end; i += 256) atomicAdd(&deg[staged[i].y], 1);
    __syncthreads();
    int v = deg[tid];
    loff[tid] = v;
    __syncthreads();
    for (int off = 1; off < 256; off <<= 1) {
        int t = (tid >= off) ? loff[tid - off] : 0;
        __syncthreads();
        loff[tid] += t;
        __syncthreads();
    }
    int excl = loff[tid] - v;
    lcur[tid] = excl;
    int n = (b << BKT_SH) + tid;
    if (n < N) row_off[n] = base + excl;
    if (b == NBKT - 1 && tid == 0) row_off[N] = E;
    __syncthreads();
    for (int i = base + tid; i < end; i += 256) {
        uint2 s = staged[i];
        int pos = atomicAdd(&lcur[s.y], 1);
        csr[base + pos] = s.x;
    }
}

// ---------------- GEMM (MFMA bf16): Hb = bf16(Xb @ W + b) ----------------

template <int DOUT>
__global__ __launch_bounds__(256) void gemm_mfma_kernel(
    const unsigned short* __restrict__ Xb,   // [N][128] bf16
    const unsigned short* __restrict__ Wt,   // swizzled [DOUT][128] bf16
    const float* __restrict__ bias,
    unsigned short* __restrict__ Hb,         // [N][DOUT] bf16
    int N) {
    constexpr int CB = DOUT / 16;
    __shared__ unsigned short wlds[DOUT * 128];
    int tid = threadIdx.x;

    constexpr int TOT16 = DOUT * 128 / 8;    // 16B units
    const uint4* Wv = reinterpret_cast<const uint4*>(Wt);
    uint4* Lv = reinterpret_cast<uint4*>(wlds);
#pragma unroll
    for (int i = 0; i < TOT16 / 256; i++) Lv[tid + i * 256] = Wv[tid + i * 256];
    __syncthreads();

    int wave = tid >> 6;
    int lane = tid & 63;
    int r0 = blockIdx.x * 64 + wave * 16;
    int arow = r0 + (lane & 15);
    int arow_c = (arow < N) ? arow : (N - 1);   // clamped loads; stores guarded

    f32x4 acc[CB];
#pragma unroll
    for (int cb = 0; cb < CB; cb++) acc[cb] = (f32x4){0.f, 0.f, 0.f, 0.f};

    const bf16x8* Xrow = reinterpret_cast<const bf16x8*>(Xb + (size_t)arow_c * 128);
    int lhi = lane >> 4;                      // k-group 0..3
#pragma unroll
    for (int kk = 0; kk < 4; kk++) {
        bf16x8 a = Xrow[kk * 4 + lhi];        // k = kk*32 + lhi*8 .. +8
#pragma unroll
        for (int cb = 0; cb < CB; cb++) {
            int colg = cb * 16 + (lane & 15);
            int kblk = kk * 4 + lhi;
            const bf16x8* bp = reinterpret_cast<const bf16x8*>(
                &wlds[colg * 128 + ((kblk ^ (colg & 7)) << 3)]);
            acc[cb] = __builtin_amdgcn_mfma_f32_16x16x32_bf16(a, *bp, acc[cb], 0, 0, 0);
        }
    }

    // C/D: col = lane&15, row = (lane>>4)*4 + r   [m89 verified]
    int cl = lane & 15;
    int rbase = r0 + lhi * 4;
#pragma unroll
    for (int cb = 0; cb < CB; cb++) {
        int colg = cb * 16 + cl;
        float bb = bias[colg];
#pragma unroll
        for (int r = 0; r < 4; r++) {
            int rowg = rbase + r;
            if (rowg < N) Hb[(size_t)rowg * DOUT + colg] = f2bf(acc[cb][r] + bb);
        }
    }
}

// ---------------- Aggregate (bf16 table): Ob = bf16(Hb[n] + sum w*Hb[src]) ----------------

template <int D>
__global__ __launch_bounds__(256) void aggregate_bf16_kernel(
    const unsigned short* __restrict__ Hb, const int* __restrict__ row_off,
    const unsigned int* __restrict__ csr, unsigned short* __restrict__ Ob, int N) {
    constexpr int TPN = D / 8;
    constexpr int NPB = 256 / TPN;
    int n = blockIdx.x * NPB + threadIdx.x / TPN;
    int d8 = threadIdx.x % TPN;
    if (n >= N) return;
    const uint4* Hv = reinterpret_cast<const uint4*>(Hb);

    float acc[8];
    {
        uint4 s = Hv[(size_t)n * TPN + d8];
        acc[0] = bflo(s.x); acc[1] = bfhi(s.x);
        acc[2] = bflo(s.y); acc[3] = bfhi(s.y);
        acc[4] = bflo(s.z); acc[5] = bfhi(s.z);
        acc[6] = bflo(s.w); acc[7] = bfhi(s.w);
    }
    auto madd = [&](uint4 v, float w) {
        acc[0] += bflo(v.x) * w; acc[1] += bfhi(v.x) * w;
        acc[2] += bflo(v.y) * w; acc[3] += bfhi(v.y) * w;
        acc[4] += bflo(v.z) * w; acc[5] += bfhi(v.z) * w;
        acc[6] += bflo(v.w) * w; acc[7] += bfhi(v.w) * w;
    };
    int e = row_off[n];
    int e1 = row_off[n + 1];
    for (; e + 4 <= e1; e += 4) {
        unsigned int c0 = csr[e], c1 = csr[e + 1], c2 = csr[e + 2], c3 = csr[e + 3];
        uint4 v0 = Hv[(size_t)(c0 & 0xFFFFu) * TPN + d8];
        uint4 v1 = Hv[(size_t)(c1 & 0xFFFFu) * TPN + d8];
        uint4 v2 = Hv[(size_t)(c2 & 0xFFFFu) * TPN + d8];
        uint4 v3 = Hv[(size_t)(c3 & 0xFFFFu) * TPN + d8];
        madd(v0, bfhi(c0));
        madd(v1, bfhi(c1));
        madd(v2, bfhi(c2));
        madd(v3, bfhi(c3));
    }
    for (; e < e1; ++e) {
        unsigned int c = csr[e];
        madd(Hv[(size_t)(c & 0xFFFFu) * TPN + d8], bfhi(c));
    }
    uint4 o;
    o.x = (unsigned int)f2bf(acc[0]) | ((unsigned int)f2bf(acc[1]) << 16);
    o.y = (unsigned int)f2bf(acc[2]) | ((unsigned int)f2bf(acc[3]) << 16);
    o.z = (unsigned int)f2bf(acc[4]) | ((unsigned int)f2bf(acc[5]) << 16);
    o.w = (unsigned int)f2bf(acc[6]) | ((unsigned int)f2bf(acc[7]) << 16);
    reinterpret_cast<uint4*>(Ob)[(size_t)n * TPN + d8] = o;
}

// ---------------- Pool ----------------

__global__ __launch_bounds__(256) void pool_kernel(const unsigned short* __restrict__ Hb,
                                                   const int* __restrict__ batch,
                                                   float* __restrict__ sums, int N,
                                                   int rows_per_blk) {
    __shared__ float bins[16 * 64];
    int tid = threadIdx.x;
    for (int i = tid; i < 1024; i += 256) bins[i] = 0.f;
    __syncthreads();
    int d4 = tid & 15;
    int rl = tid >> 4;
    int n0 = blockIdx.x * rows_per_blk;
    int n1 = min(n0 + rows_per_blk, N);
    const uint2* Hv = reinterpret_cast<const uint2*>(Hb);   // 4 bf16 per uint2
    float r0 = 0.f, r1 = 0.f, r2 = 0.f, r3 = 0.f;
    int cur = -1;
    for (int n = n0 + rl; n < n1; n += 16) {
        int b = batch[n];
        if (b != cur) {
            if (cur >= 0) {
                atomicAdd(&bins[cur * 64 + d4 * 4 + 0], r0);
                atomicAdd(&bins[cur * 64 + d4 * 4 + 1], r1);
                atomicAdd(&bins[cur * 64 + d4 * 4 + 2], r2);
                atomicAdd(&bins[cur * 64 + d4 * 4 + 3], r3);
            }
            cur = b;
            r0 = r1 = r2 = r3 = 0.f;
        }
        uint2 v = Hv[(size_t)n * 16 + d4];
        r0 += bflo(v.x); r1 += bfhi(v.x); r2 += bflo(v.y); r3 += bfhi(v.y);
    }
    if (cur >= 0) {
        atomicAdd(&bins[cur * 64 + d4 * 4 + 0], r0);
        atomicAdd(&bins[cur * 64 + d4 * 4 + 1], r1);
        atomicAdd(&bins[cur * 64 + d4 * 4 + 2], r2);
        atomicAdd(&bins[cur * 64 + d4 * 4 + 3], r3);
    }
    __syncthreads();
    for (int i = tid; i < 1024; i += 256) {
        float v = bins[i];
        if (v != 0.f) atomicAdd(&sums[i], v);
    }
}

// finalize with inline per-graph counts (batch sorted -> binary search; wave-uniform g)
__global__ void finalize_kernel(const float* __restrict__ sums, const int* __restrict__ batch,
                                int N, float* __restrict__ out) {
    int i = blockIdx.x * blockDim.x + threadIdx.x;
    if (i >= 1024) return;
    int g = i >> 6;
    auto lower_bound = [&](int key) {
        int lo = 0, hi = N;
        while (lo < hi) { int mid = (lo + hi) >> 1; if (batch[mid] < key) lo = mid + 1; else hi = mid; }
        return lo;
    };
    int c = lower_bound(g + 1) - lower_bound(g);
    out[i] = sums[i] / (float)max(c, 1);
}

// ---------------- launch ----------------

extern "C" void kernel_launch(void* const* d_in, const int* in_sizes, int n_in,
                              void* d_out, int out_size, void* d_ws, size_t ws_size,
                              hipStream_t stream) {
    const float* x   = (const float*)d_in[0];
    const int*   ei  = (const int*)d_in[1];
    const float* ea  = (const float*)d_in[2];
    const int*   bat = (const int*)d_in[3];
    const float* W1  = (const float*)d_in[4];
    const float* b1  = (const float*)d_in[5];
    const float* W2  = (const float*)d_in[6];
    const float* b2  = (const float*)d_in[7];
    const float* W3  = (const float*)d_in[8];
    const float* b3  = (const float*)d_in[9];

    const int N = in_sizes[0] / 128;
    const int E = in_sizes[2];
    const int* src = ei;
    const int* dst = ei + E;
    const int NBKT = (N + BKT_NODES - 1) / BKT_NODES;
    const int CPB = (E + NBLK_SC - 1) / NBLK_SC;
    const int CTOT = NBKT * NBLK_SC;

    auto align = [](size_t v) { return (v + 255) & ~(size_t)255; };
    char* p = (char*)d_ws;
    unsigned short* Xb   = (unsigned short*)p; p += align((size_t)N * 128 * 2);
    unsigned short* Hb   = (unsigned short*)p; p += align((size_t)N * 128 * 2);
    unsigned short* Ab   = (unsigned short*)p; p += align((size_t)N * 128 * 2);
    unsigned short* Ab3  = (unsigned short*)p; p += align((size_t)N * 64 * 2);
    unsigned short* Wt1  = (unsigned short*)p; p += align(128 * 128 * 2);
    unsigned short* Wt2  = (unsigned short*)p; p += align(128 * 128 * 2);
    unsigned short* Wt3  = (unsigned short*)p; p += align(64 * 128 * 2);
    int*   row_off  = (int*)p;   p += align((size_t)(N + 1) * sizeof(int));
    int*   cnt      = (int*)p;   p += align((size_t)CTOT * sizeof(int));
    int*   scan     = (int*)p;   p += align((size_t)CTOT * sizeof(int));
    uint2* staged   = (uint2*)p; p += align((size_t)E * sizeof(uint2));
    unsigned int* csr = (unsigned int*)p; p += align((size_t)E * sizeof(unsigned int));
    float* sums     = (float*)p; p += align(1024 * sizeof(float));

    hipMemsetAsync(sums, 0, 1024 * sizeof(float), stream);

    // fused prep: x->bf16 (xblocks), W-prep (20 blocks)
    int n4 = N * 128 / 4;
    int xblocks = (n4 + 255) / 256;
    prep_kernel<<<xblocks + 20, 256, 0, stream>>>(
        x, Xb, n4, xblocks, W1, Wt1, W2, Wt2, W3, Wt3);

    // CSR build: segmented counting sort
    csr_hist_kernel<<<NBLK_SC, 256, 0, stream>>>(dst, cnt, E, NBKT, CPB);
    csr_scan_kernel<<<1, 1024, 0, stream>>>(cnt, scan, CTOT);
    csr_scatter_kernel<<<NBLK_SC, 256, 0, stream>>>(src, dst, ea, scan, staged, E, NBKT, CPB);
    csr_bucket_kernel<<<NBKT, 256, 0, stream>>>(scan, staged, csr, row_off, N, E);

    int gb = (N + 63) / 64;
    // layer 1
    gemm_mfma_kernel<128><<<gb, 256, 0, stream>>>(Xb, Wt1, b1, Hb, N);
    aggregate_bf16_kernel<128><<<(N + 15) / 16, 256, 0, stream>>>(Hb, row_off, csr, Ab, N);
    // layer 2
    gemm_mfma_kernel<128><<<gb, 256, 0, stream>>>(Ab, Wt2, b2, Hb, N);
    aggregate_bf16_kernel<128><<<(N + 15) / 16, 256, 0, stream>>>(Hb, row_off, csr, Ab, N);
    // layer 3 (DOUT = 64)
    gemm_mfma_kernel<64><<<gb, 256, 0, stream>>>(Ab, Wt3, b3, Hb, N);
    aggregate_bf16_kernel<64><<<(N + 31) / 32, 256, 0, stream>>>(Hb, row_off, csr, Ab3, N);

    // pool
    int pool_blocks = 512;
    int rows_per_blk = (N + pool_blocks - 1) / pool_blocks;
    pool_kernel<<<pool_blocks, 256, 0, stream>>>(Ab3, bat, sums, N, rows_per_blk);
    finalize_kernel<<<4, 256, 0, stream>>>(sums, bat, N, (float*)d_out);
}

// Round 14
// 252.602 us; speedup vs baseline: 1.2638x; 1.2638x over previous
//
#include <hip/hip_runtime.h>
#include <hip/hip_bf16.h>

typedef __bf16 bf16x8 __attribute__((ext_vector_type(8)));
typedef float f32x4 __attribute__((ext_vector_type(4)));

#define NBLK_SC 256              // scatter blocks (chunks)
#define BKT_SH 8                 // 256 nodes per bucket
#define BKT_NODES 256

__device__ __forceinline__ unsigned short f2bf(float f) {
    unsigned int u = __float_as_uint(f);
    unsigned int r = (u + 0x7FFFu + ((u >> 16) & 1u)) >> 16;   // RNE
    return (unsigned short)r;
}
__device__ __forceinline__ float bflo(unsigned int u) { return __uint_as_float(u << 16); }
__device__ __forceinline__ float bfhi(unsigned int u) { return __uint_as_float(u & 0xffff0000u); }

// ---------------- fused prep: x->bf16 | W1/W2/W3 transpose+swizzle ----------------

__device__ __forceinline__ void prep_w_dev(const float* __restrict__ W,
                                           unsigned short* __restrict__ Wt,
                                           int DOUT, int i) {
    int col = i >> 4;
    int kblk = i & 15;
    size_t off = (size_t)col * 128 + (size_t)((kblk ^ (col & 7)) << 3);
#pragma unroll
    for (int j = 0; j < 8; j++)
        Wt[off + j] = f2bf(W[(kblk * 8 + j) * DOUT + col]);
}

__global__ __launch_bounds__(256) void prep_kernel(
    const float* __restrict__ x, unsigned short* __restrict__ Xb, int n4, int xblocks,
    const float* __restrict__ W1, unsigned short* __restrict__ Wt1,
    const float* __restrict__ W2, unsigned short* __restrict__ Wt2,
    const float* __restrict__ W3, unsigned short* __restrict__ Wt3) {
    int b = blockIdx.x;
    int tid = threadIdx.x;
    if (b < xblocks) {
        int i = b * 256 + tid;
        if (i < n4) {
            float4 v = reinterpret_cast<const float4*>(x)[i];
            ushort4 o;
            o.x = f2bf(v.x); o.y = f2bf(v.y); o.z = f2bf(v.z); o.w = f2bf(v.w);
            reinterpret_cast<ushort4*>(Xb)[i] = o;
        }
        return;
    }
    b -= xblocks;
    if (b < 8) {
        prep_w_dev(W1, Wt1, 128, b * 256 + tid);
    } else if (b < 16) {
        prep_w_dev(W2, Wt2, 128, (b - 8) * 256 + tid);
    } else {
        int i = (b - 16) * 256 + tid;
        if (i < 64 * 16) prep_w_dev(W3, Wt3, 64, i);
    }
}

// ---------------- CSR build: segmented counting sort (no global atomics) ----------------

// pass A: per-chunk histogram over buckets -> cnt[bucket*NBLK + chunk]
__global__ __launch_bounds__(256) void csr_hist_kernel(const int* __restrict__ dst,
                                                       int* __restrict__ cnt,
                                                       int E, int NBKT, int CPB) {
    __shared__ int lcnt[BKT_NODES];
    int j = blockIdx.x;
    int tid = threadIdx.x;
    lcnt[tid] = 0;
    __syncthreads();
    int e0 = j * CPB, e1 = min(e0 + CPB, E);
    for (int e = e0 + tid; e < e1; e += 256) atomicAdd(&lcnt[dst[e] >> BKT_SH], 1);
    __syncthreads();
    for (int b = tid; b < NBKT; b += 256) cnt[b * NBLK_SC + j] = lcnt[b];
}

// pass B: parallel 3-kernel exclusive scan over cnt (CTOT entries)
__global__ __launch_bounds__(1024) void pscan1_kernel(const int* __restrict__ cnt,
                                                      int* __restrict__ scan,
                                                      int* __restrict__ bsums, int total) {
    __shared__ int s[1024];
    int tid = threadIdx.x;
    int i = blockIdx.x * 1024 + tid;
    int v = (i < total) ? cnt[i] : 0;
    s[tid] = v;
    __syncthreads();
    for (int off = 1; off < 1024; off <<= 1) {
        int t = (tid >= off) ? s[tid - off] : 0;
        __syncthreads();
        s[tid] += t;
        __syncthreads();
    }
    if (i < total) scan[i] = s[tid] - v;
    if (tid == 1023) bsums[blockIdx.x] = s[1023];
}

__global__ void pscan2_kernel(int* __restrict__ blk, int nb) {
    __shared__ int s[128];
    int t = threadIdx.x;
    int v = (t < nb) ? blk[t] : 0;
    s[t] = v;
    __syncthreads();
    for (int off = 1; off < 128; off <<= 1) {
        int u = (t >= off) ? s[t - off] : 0;
        __syncthreads();
        s[t] += u;
        __syncthreads();
    }
    if (t < nb) blk[t] = s[t] - v;
}

__global__ __launch_bounds__(1024) void pscan3_kernel(int* __restrict__ scan,
                                                      const int* __restrict__ bsums, int total) {
    int i = blockIdx.x * 1024 + threadIdx.x;
    if (i < total) scan[i] += bsums[blockIdx.x];
}

// pass C: scatter into staged; each (bucket,chunk) segment has a single writer block
__global__ __launch_bounds__(256) void csr_scatter_kernel(const int* __restrict__ src,
                                                          const int* __restrict__ dst,
                                                          const float* __restrict__ ea,
                                                          const int* __restrict__ scan,
                                                          uint2* __restrict__ staged,
                                                          int E, int NBKT, int CPB) {
    __shared__ int curs[BKT_NODES];
    int j = blockIdx.x;
    int tid = threadIdx.x;
    for (int b = tid; b < NBKT; b += 256) curs[b] = scan[b * NBLK_SC + j];
    __syncthreads();
    int e0 = j * CPB, e1 = min(e0 + CPB, E);
    for (int e = e0 + tid; e < e1; e += 256) {
        int d = dst[e];
        int pos = atomicAdd(&curs[d >> BKT_SH], 1);
        staged[pos] = make_uint2((unsigned int)src[e] | ((unsigned int)f2bf(ea[e]) << 16),
                                 (unsigned int)(d & (BKT_NODES - 1)));
    }
}

// pass D: per bucket: LDS degree+scan -> row_off; in-bucket sort -> csr
__global__ __launch_bounds__(256) void csr_bucket_kernel(const int* __restrict__ scan,
                                                         const uint2* __restrict__ staged,
                                                         unsigned int* __restrict__ csr,
                                                         int* __restrict__ row_off,
                                                         int N, int E) {
    __shared__ int deg[BKT_NODES];
    __shared__ int loff[BKT_NODES];
    __shared__ int lcur[BKT_NODES];
    int b = blockIdx.x;
    int NBKT = gridDim.x;
    int tid = threadIdx.x;
    int base = scan[b * NBLK_SC];
    int end = (b == NBKT - 1) ? E : scan[(b + 1) * NBLK_SC];
    deg[tid] = 0;
    __syncthreads();
    for (int i = base + tid; i < end; i += 256) atomicAdd(&deg[staged[i].y], 1);
    __syncthreads();
    int v = deg[tid];
    loff[tid] = v;
    __syncthreads();
    for (int off = 1; off < 256; off <<= 1) {
        int t = (tid >= off) ? loff[tid - off] : 0;
        __syncthreads();
        loff[tid] += t;
        __syncthreads();
    }
    int excl = loff[tid] - v;
    lcur[tid] = excl;
    int n = (b << BKT_SH) + tid;
    if (n < N) row_off[n] = base + excl;
    if (b == NBKT - 1 && tid == 0) row_off[N] = E;
    __syncthreads();
    for (int i = base + tid; i < end; i += 256) {
        uint2 s = staged[i];
        int pos = atomicAdd(&lcur[s.y], 1);
        csr[base + pos] = s.x;
    }
}

// ---------------- GEMM (MFMA bf16): Hb = bf16(Xb @ W + b) ----------------

template <int DOUT>
__global__ __launch_bounds__(256) void gemm_mfma_kernel(
    const unsigned short* __restrict__ Xb,   // [N][128] bf16
    const unsigned short* __restrict__ Wt,   // swizzled [DOUT][128] bf16
    const float* __restrict__ bias,
    unsigned short* __restrict__ Hb,         // [N][DOUT] bf16
    int N) {
    constexpr int CB = DOUT / 16;
    __shared__ unsigned short wlds[DOUT * 128];
    int tid = threadIdx.x;

    constexpr int TOT16 = DOUT * 128 / 8;    // 16B units
    const uint4* Wv = reinterpret_cast<const uint4*>(Wt);
    uint4* Lv = reinterpret_cast<uint4*>(wlds);
#pragma unroll
    for (int i = 0; i < TOT16 / 256; i++) Lv[tid + i * 256] = Wv[tid + i * 256];
    __syncthreads();

    int wave = tid >> 6;
    int lane = tid & 63;
    int r0 = blockIdx.x * 64 + wave * 16;
    int arow = r0 + (lane & 15);
    int arow_c = (arow < N) ? arow : (N - 1);   // clamped loads; stores guarded

    f32x4 acc[CB];
#pragma unroll
    for (int cb = 0; cb < CB; cb++) acc[cb] = (f32x4){0.f, 0.f, 0.f, 0.f};

    const bf16x8* Xrow = reinterpret_cast<const bf16x8*>(Xb + (size_t)arow_c * 128);
    int lhi = lane >> 4;                      // k-group 0..3
#pragma unroll
    for (int kk = 0; kk < 4; kk++) {
        bf16x8 a = Xrow[kk * 4 + lhi];        // k = kk*32 + lhi*8 .. +8
#pragma unroll
        for (int cb = 0; cb < CB; cb++) {
            int colg = cb * 16 + (lane & 15);
            int kblk = kk * 4 + lhi;
            const bf16x8* bp = reinterpret_cast<const bf16x8*>(
                &wlds[colg * 128 + ((kblk ^ (colg & 7)) << 3)]);
            acc[cb] = __builtin_amdgcn_mfma_f32_16x16x32_bf16(a, *bp, acc[cb], 0, 0, 0);
        }
    }

    // C/D: col = lane&15, row = (lane>>4)*4 + r   [m89 verified]
    int cl = lane & 15;
    int rbase = r0 + lhi * 4;
#pragma unroll
    for (int cb = 0; cb < CB; cb++) {
        int colg = cb * 16 + cl;
        float bb = bias[colg];
#pragma unroll
        for (int r = 0; r < 4; r++) {
            int rowg = rbase + r;
            if (rowg < N) Hb[(size_t)rowg * DOUT + colg] = f2bf(acc[cb][r] + bb);
        }
    }
}

// ---------------- Aggregate (bf16 table): Ob = bf16(Hb[n] + sum w*Hb[src]) ----------------

template <int D>
__global__ __launch_bounds__(256) void aggregate_bf16_kernel(
    const unsigned short* __restrict__ Hb, const int* __restrict__ row_off,
    const unsigned int* __restrict__ csr, unsigned short* __restrict__ Ob, int N) {
    constexpr int TPN = D / 8;
    constexpr int NPB = 256 / TPN;
    int n = blockIdx.x * NPB + threadIdx.x / TPN;
    int d8 = threadIdx.x % TPN;
    if (n >= N) return;
    const uint4* Hv = reinterpret_cast<const uint4*>(Hb);

    float acc[8];
    {
        uint4 s = Hv[(size_t)n * TPN + d8];
        acc[0] = bflo(s.x); acc[1] = bfhi(s.x);
        acc[2] = bflo(s.y); acc[3] = bfhi(s.y);
        acc[4] = bflo(s.z); acc[5] = bfhi(s.z);
        acc[6] = bflo(s.w); acc[7] = bfhi(s.w);
    }
    auto madd = [&](uint4 v, float w) {
        acc[0] += bflo(v.x) * w; acc[1] += bfhi(v.x) * w;
        acc[2] += bflo(v.y) * w; acc[3] += bfhi(v.y) * w;
        acc[4] += bflo(v.z) * w; acc[5] += bfhi(v.z) * w;
        acc[6] += bflo(v.w) * w; acc[7] += bfhi(v.w) * w;
    };
    int e = row_off[n];
    int e1 = row_off[n + 1];
    for (; e + 4 <= e1; e += 4) {
        unsigned int c0 = csr[e], c1 = csr[e + 1], c2 = csr[e + 2], c3 = csr[e + 3];
        uint4 v0 = Hv[(size_t)(c0 & 0xFFFFu) * TPN + d8];
        uint4 v1 = Hv[(size_t)(c1 & 0xFFFFu) * TPN + d8];
        uint4 v2 = Hv[(size_t)(c2 & 0xFFFFu) * TPN + d8];
        uint4 v3 = Hv[(size_t)(c3 & 0xFFFFu) * TPN + d8];
        madd(v0, bfhi(c0));
        madd(v1, bfhi(c1));
        madd(v2, bfhi(c2));
        madd(v3, bfhi(c3));
    }
    for (; e < e1; ++e) {
        unsigned int c = csr[e];
        madd(Hv[(size_t)(c & 0xFFFFu) * TPN + d8], bfhi(c));
    }
    uint4 o;
    o.x = (unsigned int)f2bf(acc[0]) | ((unsigned int)f2bf(acc[1]) << 16);
    o.y = (unsigned int)f2bf(acc[2]) | ((unsigned int)f2bf(acc[3]) << 16);
    o.z = (unsigned int)f2bf(acc[4]) | ((unsigned int)f2bf(acc[5]) << 16);
    o.w = (unsigned int)f2bf(acc[6]) | ((unsigned int)f2bf(acc[7]) << 16);
    reinterpret_cast<uint4*>(Ob)[(size_t)n * TPN + d8] = o;
}

// ---------------- Pool ----------------

__global__ __launch_bounds__(256) void pool_kernel(const unsigned short* __restrict__ Hb,
                                                   const int* __restrict__ batch,
                                                   float* __restrict__ sums, int N,
                                                   int rows_per_blk) {
    __shared__ float bins[16 * 64];
    int tid = threadIdx.x;
    for (int i = tid; i < 1024; i += 256) bins[i] = 0.f;
    __syncthreads();
    int d4 = tid & 15;
    int rl = tid >> 4;
    int n0 = blockIdx.x * rows_per_blk;
    int n1 = min(n0 + rows_per_blk, N);
    const uint2* Hv = reinterpret_cast<const uint2*>(Hb);   // 4 bf16 per uint2
    float r0 = 0.f, r1 = 0.f, r2 = 0.f, r3 = 0.f;
    int cur = -1;
    for (int n = n0 + rl; n < n1; n += 16) {
        int b = batch[n];
        if (b != cur) {
            if (cur >= 0) {
                atomicAdd(&bins[cur * 64 + d4 * 4 + 0], r0);
                atomicAdd(&bins[cur * 64 + d4 * 4 + 1], r1);
                atomicAdd(&bins[cur * 64 + d4 * 4 + 2], r2);
                atomicAdd(&bins[cur * 64 + d4 * 4 + 3], r3);
            }
            cur = b;
            r0 = r1 = r2 = r3 = 0.f;
        }
        uint2 v = Hv[(size_t)n * 16 + d4];
        r0 += bflo(v.x); r1 += bfhi(v.x); r2 += bflo(v.y); r3 += bfhi(v.y);
    }
    if (cur >= 0) {
        atomicAdd(&bins[cur * 64 + d4 * 4 + 0], r0);
        atomicAdd(&bins[cur * 64 + d4 * 4 + 1], r1);
        atomicAdd(&bins[cur * 64 + d4 * 4 + 2], r2);
        atomicAdd(&bins[cur * 64 + d4 * 4 + 3], r3);
    }
    __syncthreads();
    for (int i = tid; i < 1024; i += 256) {
        float v = bins[i];
        if (v != 0.f) atomicAdd(&sums[i], v);
    }
}

// finalize with inline per-graph counts (batch sorted -> binary search; wave-uniform g)
__global__ void finalize_kernel(const float* __restrict__ sums, const int* __restrict__ batch,
                                int N, float* __restrict__ out) {
    int i = blockIdx.x * blockDim.x + threadIdx.x;
    if (i >= 1024) return;
    int g = i >> 6;
    auto lower_bound = [&](int key) {
        int lo = 0, hi = N;
        while (lo < hi) { int mid = (lo + hi) >> 1; if (batch[mid] < key) lo = mid + 1; else hi = mid; }
        return lo;
    };
    int c = lower_bound(g + 1) - lower_bound(g);
    out[i] = sums[i] / (float)max(c, 1);
}

// ---------------- launch ----------------

extern "C" void kernel_launch(void* const* d_in, const int* in_sizes, int n_in,
                              void* d_out, int out_size, void* d_ws, size_t ws_size,
                              hipStream_t stream) {
    const float* x   = (const float*)d_in[0];
    const int*   ei  = (const int*)d_in[1];
    const float* ea  = (const float*)d_in[2];
    const int*   bat = (const int*)d_in[3];
    const float* W1  = (const float*)d_in[4];
    const float* b1  = (const float*)d_in[5];
    const float* W2  = (const float*)d_in[6];
    const float* b2  = (const float*)d_in[7];
    const float* W3  = (const float*)d_in[8];
    const float* b3  = (const float*)d_in[9];

    const int N = in_sizes[0] / 128;
    const int E = in_sizes[2];
    const int* src = ei;
    const int* dst = ei + E;
    const int NBKT = (N + BKT_NODES - 1) / BKT_NODES;
    const int CPB = (E + NBLK_SC - 1) / NBLK_SC;
    const int CTOT = NBKT * NBLK_SC;

    auto align = [](size_t v) { return (v + 255) & ~(size_t)255; };
    char* p = (char*)d_ws;
    unsigned short* Xb   = (unsigned short*)p; p += align((size_t)N * 128 * 2);
    unsigned short* Hb   = (unsigned short*)p; p += align((size_t)N * 128 * 2);
    unsigned short* Ab   = (unsigned short*)p; p += align((size_t)N * 128 * 2);
    unsigned short* Ab3  = (unsigned short*)p; p += align((size_t)N * 64 * 2);
    unsigned short* Wt1  = (unsigned short*)p; p += align(128 * 128 * 2);
    unsigned short* Wt2  = (unsigned short*)p; p += align(128 * 128 * 2);
    unsigned short* Wt3  = (unsigned short*)p; p += align(64 * 128 * 2);
    int*   row_off  = (int*)p;   p += align((size_t)(N + 1) * sizeof(int));
    int*   cnt      = (int*)p;   p += align((size_t)CTOT * sizeof(int));
    int*   scan     = (int*)p;   p += align((size_t)CTOT * sizeof(int));
    int*   bsums    = (int*)p;   p += align(128 * sizeof(int));
    uint2* staged   = (uint2*)p; p += align((size_t)E * sizeof(uint2));
    unsigned int* csr = (unsigned int*)p; p += align((size_t)E * sizeof(unsigned int));
    float* sums     = (float*)p; p += align(1024 * sizeof(float));

    hipMemsetAsync(sums, 0, 1024 * sizeof(float), stream);

    // fused prep: x->bf16 (xblocks), W-prep (20 blocks)
    int n4 = N * 128 / 4;
    int xblocks = (n4 + 255) / 256;
    prep_kernel<<<xblocks + 20, 256, 0, stream>>>(
        x, Xb, n4, xblocks, W1, Wt1, W2, Wt2, W3, Wt3);

    // CSR build: segmented counting sort with parallel scan
    int sb = (CTOT + 1023) / 1024;           // scan blocks (<=128)
    csr_hist_kernel<<<NBLK_SC, 256, 0, stream>>>(dst, cnt, E, NBKT, CPB);
    pscan1_kernel<<<sb, 1024, 0, stream>>>(cnt, scan, bsums, CTOT);
    pscan2_kernel<<<1, 128, 0, stream>>>(bsums, sb);
    pscan3_kernel<<<sb, 1024, 0, stream>>>(scan, bsums, CTOT);
    csr_scatter_kernel<<<NBLK_SC, 256, 0, stream>>>(src, dst, ea, scan, staged, E, NBKT, CPB);
    csr_bucket_kernel<<<NBKT, 256, 0, stream>>>(scan, staged, csr, row_off, N, E);

    int gb = (N + 63) / 64;
    // layer 1
    gemm_mfma_kernel<128><<<gb, 256, 0, stream>>>(Xb, Wt1, b1, Hb, N);
    aggregate_bf16_kernel<128><<<(N + 15) / 16, 256, 0, stream>>>(Hb, row_off, csr, Ab, N);
    // layer 2
    gemm_mfma_kernel<128><<<gb, 256, 0, stream>>>(Ab, Wt2, b2, Hb, N);
    aggregate_bf16_kernel<128><<<(N + 15) / 16, 256, 0, stream>>>(Hb, row_off, csr, Ab, N);
    // layer 3 (DOUT = 64)
    gemm_mfma_kernel<64><<<gb, 256, 0, stream>>>(Ab, Wt3, b3, Hb, N);
    aggregate_bf16_kernel<64><<<(N + 31) / 32, 256, 0, stream>>>(Hb, row_off, csr, Ab3, N);

    // pool
    int pool_blocks = 512;
    int rows_per_blk = (N + pool_blocks - 1) / pool_blocks;
    pool_kernel<<<pool_blocks, 256, 0, stream>>>(Ab3, bat, sums, N, rows_per_blk);
    finalize_kernel<<<4, 256, 0, stream>>>(sums, bat, N, (float*)d_out);
}